// Round 7
// baseline (1769.393 us; speedup 1.0000x reference)
//
#include <hip/hip_runtime.h>
#include <cstdint>
#include <cstddef>

// RNNDecoder: B=32, T=64, S=400, V=50257, DW=DM=DE=512, DK=64, POOL=2
// Round-7 = round-6 resubmit (container infra failure, kernel audited clean).
// Recurrence runs on 32 blocks (one per batch) -> barrier domain shrinks
// 256->32 (less skew, 1-wave poll), and the 8x per-batch replication of attn
// phases / gb reads disappears. Blocks 32..255 sleep until the loop
// completes, then all 256 blocks do the readout+copy_gate tail.
// Coherence (validated r3-r5): mutable cross-block data -> step-unique
// addresses, sc1 write-through stores, consumers use normal cached loads
// (write-once-then-read + dispatch-boundary invalidate => never stale).

#define PAD_ID_C 50256

typedef float f32x4 __attribute__((ext_vector_type(4)));
typedef short bf16x8 __attribute__((ext_vector_type(8)));

__device__ __forceinline__ unsigned short f2bf(float x){
  union { float f; unsigned u; } v; v.f = x;
  unsigned r = (v.u + 0x7FFFu + ((v.u >> 16) & 1u)) >> 16;
  return (unsigned short)r;
}
__device__ __forceinline__ float bf2f(unsigned short h){
  union { unsigned u; float f; } v; v.u = ((unsigned)h) << 16; return v.f;
}
__device__ __forceinline__ float sigm_(float x){ return 1.f/(1.f+__expf(-x)); }
__device__ __forceinline__ float tanh_(float x){ float e=__expf(2.f*x); return 1.f - 2.f/(e+1.f); }

// sc1 write-through stores (bypass L2, land at IC) for cross-block data
__device__ __forceinline__ void cstf(float* p, float v){
  __hip_atomic_store(p, v, __ATOMIC_RELAXED, __HIP_MEMORY_SCOPE_AGENT);
}
__device__ __forceinline__ void csts(unsigned short* p, unsigned short v){
  __hip_atomic_store(p, v, __ATOMIC_RELAXED, __HIP_MEMORY_SCOPE_AGENT);
}

// packed A-activation index for [32][512] src -> tiles (mt,kt,lane,8)
__device__ __forceinline__ int pkidx(int b, int d){
  return ((((b>>4)*16) + (d>>5))*64 + (((d>>3)&3)*16) + (b&15))*8 + (d&7);
}

// ---------------- init kernels ----------------

__global__ void k_pack(const float* __restrict__ W, unsigned short* __restrict__ pk, int N, int K){
  int ktc = K >> 5;
  int gid = blockIdx.x*256 + threadIdx.x;
  int total = (N>>4)*ktc*64;
  if (gid >= total) return;
  int lane = gid & 63;
  int rem = gid >> 6;
  int kt = rem % ktc, nt = rem / ktc;
  int k0 = kt*32 + (lane>>4)*8;
  int n  = nt*16 + (lane&15);
  #pragma unroll
  for (int j=0;j<8;j++) pk[gid*8+j] = f2bf(W[(k0+j)*N + n]);
}

// wq transposed to [k][d] + zero the barrier region
__global__ void k_misc(const float* __restrict__ Wq, unsigned short* __restrict__ wq_t,
                       int* __restrict__ barz){
  int idx = blockIdx.x*256 + threadIdx.x;
  if (idx < 32768){ int k = idx >> 9, d = idx & 511; wq_t[idx] = f2bf(Wq[d*64+k]); }
  else if (idx < 32768 + 4112) barz[idx - 32768] = 0;
}

__global__ void k_emb(const int* __restrict__ tgt, const float* __restrict__ word_emb,
                      unsigned short* __restrict__ emb_pk){
  int bid = blockIdx.x;           // t*32+b
  int t = bid >> 5, b = bid & 31;
  int token = tgt[b*64 + t];
  const float* src = word_emb + (size_t)token*512;
  for (int d = threadIdx.x; d < 512; d += 256){
    int idx = (((t*2 + (b>>4))*16 + (d>>5))*64 + ((d>>3)&3)*16 + (b&15))*8 + (d&7);
    emb_pk[idx] = f2bf(src[d]);
  }
}

// fused: pre_t ([b][s][64]) GEMV + enc_bf conversion for the same (b,s) row
__global__ void k_pre(const float* __restrict__ enc, const float* __restrict__ Wc,
                      unsigned short* __restrict__ pre_t,
                      unsigned short* __restrict__ enc_bf){
  __shared__ float part[4][64];
  int bs = blockIdx.x;            // b*400+s
  int k = threadIdx.x & 63, dp = threadIdx.x >> 6;   // 256 threads
  const float* e = enc + (size_t)bs*512;
  float acc = 0.f;
  #pragma unroll 4
  for (int d = dp*128; d < dp*128 + 128; d++) acc += e[d]*Wc[d*64+k];
  part[dp][k] = acc;
  // enc_bf: thread (dp,k) writes d = dp*128 + 2k, 2k+1
  {
    int d0 = dp*128 + k*2;
    enc_bf[(size_t)bs*512 + d0]     = f2bf(e[d0]);
    enc_bf[(size_t)bs*512 + d0 + 1] = f2bf(e[d0+1]);
  }
  __syncthreads();
  if (threadIdx.x < 64){
    float a = part[0][k] + part[1][k] + part[2][k] + part[3][k];
    pre_t[(size_t)bs*64 + k] = f2bf(a);
  }
}

// h0 = tanh(hidden@W_init + b_init) into slot-0 state arrays; ctx0 = 0
__global__ void k_h0(const float* __restrict__ hidden, const float* __restrict__ W_init,
                     const float* __restrict__ b_init,
                     float* __restrict__ hf0, unsigned short* __restrict__ hpk0,
                     float* __restrict__ cf0, unsigned short* __restrict__ cpk0){
  int b = blockIdx.x, jj = threadIdx.x;   // 32 x 512
  const float* hv = hidden + b*512;
  float acc = 0.f;
  for (int d=0; d<512; d++) acc += hv[d]*W_init[d*512+jj];
  float h = tanh_(acc + b_init[jj]);
  hf0[b*512+jj] = h;
  hpk0[pkidx(b,jj)] = f2bf(h);
  cf0[b*512+jj] = 0.f;
  cpk0[b*512+jj] = 0;   // zeros in any layout are zeros
}

// gxe = emb @ Wx[0:512] + bx + [bh;bh;0]  (hoisted out of the loop)
__global__ void k_gxe(const unsigned short* __restrict__ emb_pk,
                      const unsigned short* __restrict__ wxe,
                      const float* __restrict__ bx, const float* __restrict__ bh,
                      float* __restrict__ gxe){
  int job = blockIdx.x*4 + (threadIdx.x>>6);   // 12288 jobs = 128 mtg x 96 nt
  int lane = threadIdx.x & 63;
  int nt = job % 96, mtg = job / 96;
  f32x4 acc = {0.f,0.f,0.f,0.f};
  const bf16x8* ae = (const bf16x8*)emb_pk + (size_t)(mtg*16)*64 + lane;
  const bf16x8* wp = (const bf16x8*)wxe + (size_t)(nt*16)*64 + lane;
  #pragma unroll
  for (int kt=0; kt<16; kt++)
    acc = __builtin_amdgcn_mfma_f32_16x16x32_bf16(ae[kt*64], wp[kt*64], acc, 0,0,0);
  int row = mtg*16 + (lane>>4)*4, col = nt*16 + (lane&15);
  float badd = bx[col] + (col < 1024 ? bh[col] : 0.f);
  #pragma unroll
  for (int i=0;i<4;i++) gxe[(size_t)(row+i)*1536 + col] = acc[i] + badd;
}

// ---------------- persistent step kernel ----------------

struct PP {
  const unsigned short *emb, *wxc, *wh, *wr, *wq, *pre, *enc;
  const float *gxe;                         // [2048][1536] emb-part + biases
  unsigned short *hpk, *cpk;                // 65 slots x 16384 shorts
  float *gb;                                // 64 slots x [32][2048] gate buf
  float *hf, *cf;                           // 65 slots x 16384 floats
  const float *Wcopy, *bcopy, *bh, *bread, *wcov, *vatt;
  const int* src;
  float *out_pred, *out_attnlast, *out_ctxf, *out_copypred, *out_gate, *out_covloss;
  int *arr;     // 32 x 16 ints (one cacheline per recurrence block)
};

// 32-block all-gather barrier: block stores its arrival word (sc1); one wave
// (tid<32) polls all 32 lines. Monotonic idx; arr zeroed by k_misc.
__device__ __forceinline__ void gridbar32(int* arr, int idx){
  asm volatile("s_waitcnt vmcnt(0) lgkmcnt(0)" ::: "memory");
  __syncthreads();
  if (threadIdx.x == 0)
    __hip_atomic_store(arr + blockIdx.x*16, idx, __ATOMIC_RELAXED, __HIP_MEMORY_SCOPE_AGENT);
  if (threadIdx.x < 32){
    while (__hip_atomic_load(arr + threadIdx.x*16, __ATOMIC_RELAXED, __HIP_MEMORY_SCOPE_AGENT) < idx){}
  }
  __syncthreads();
}

__device__ __forceinline__ float blockReduceSum(float v, float* redw, int tid){
  #pragma unroll
  for (int off=32; off; off>>=1) v += __shfl_down(v, off, 64);
  if ((tid & 63) == 0) redw[tid>>6] = v;
  __syncthreads();
  if (tid == 0){
    float r = 0.f;
    #pragma unroll
    for (int i=0;i<8;i++) r += redw[i];
    redw[8] = r;
  }
  __syncthreads();
  return redw[8];
}

__global__ __launch_bounds__(512,1) void k_steps(PP p){
  __shared__ float h_s[512];
  __shared__ float gxe_s[1536];
  __shared__ float hq_part[8][64];
  __shared__ float hq_s[64];
  __shared__ float wv_s[128];
  __shared__ float p_s[400];
  __shared__ float redw[16];
  __shared__ float cred[8][512];

  const int tid = threadIdx.x;

  if (blockIdx.x >= 32){
    // helper block: sleep until the recurrence completes (all 32 lines = 128)
    if (tid < 32){
      while (__hip_atomic_load(p.arr + tid*16, __ATOMIC_RELAXED, __HIP_MEMORY_SCOPE_AGENT) < 128)
        __builtin_amdgcn_s_sleep(16);
    }
    __syncthreads();
  } else {
    const int b = blockIdx.x;
    int idx = 0;
    float c_reg = 0.f;               // coverage for s=tid

    // hoisted invariants
    if (tid < 128) wv_s[tid] = (tid < 64) ? p.wcov[tid] : p.vatt[tid-64];
    h_s[tid] = p.hf[b*512 + tid];                       // h(-1)=h0, slot 0
    const bool padv = (tid < 400) ? (p.src[b*400+tid] == PAD_ID_C) : true;
    const float bh2r = p.bh[1024 + tid];
    bf16x8 wqreg[8];                                    // Wq row slice, constant
    {
      int k = tid & 63, pr = tid >> 6;
      const bf16x8* wrow = (const bf16x8*)(p.wq + k*512 + pr*64);
      #pragma unroll
      for (int c=0;c<8;c++) wqreg[c] = wrow[c];
    }
    __syncthreads();

    for (int t = 0; t < 64; ++t){
      const unsigned short* hpk_t = p.hpk + (size_t)t*16384;
      const unsigned short* cpk_t = p.cpk + (size_t)t*16384;
      float* gb_t = p.gb + (size_t)t*65536;

      // ------- GEMM phase: waves 0..5 do fused gx+gh jobs (192 jobs over
      // ------- 32 blocks); waves 6,7 prefetch gxe row into LDS.
      {
        int wib = tid >> 6, lane = tid & 63;
        if (wib < 6){
          int wv = wib*32 + blockIdx.x;    // 0..191, block-fixed -> L2-hot weights
          int nt = wv % 96, mt = wv / 96;
          f32x4 aX = {0.f,0.f,0.f,0.f}, aH = {0.f,0.f,0.f,0.f};
          const bf16x8* wpX = (const bf16x8*)p.wxc + (size_t)(nt*16)*64 + lane;
          const bf16x8* wpH = (const bf16x8*)p.wh  + (size_t)(nt*16)*64 + lane;
          const bf16x8* ac = (const bf16x8*)cpk_t + (size_t)(mt*16)*64 + lane;
          const bf16x8* ah = (const bf16x8*)hpk_t + (size_t)(mt*16)*64 + lane;
          #pragma unroll
          for (int kt=0; kt<16; kt++){
            aX = __builtin_amdgcn_mfma_f32_16x16x32_bf16(ac[kt*64], wpX[kt*64], aX, 0,0,0);
            aH = __builtin_amdgcn_mfma_f32_16x16x32_bf16(ah[kt*64], wpH[kt*64], aH, 0,0,0);
          }
          int row = mt*16 + (lane>>4)*4, col = nt*16 + (lane&15);
          if (col < 1024){
            #pragma unroll
            for (int i=0;i<4;i++) cstf(&gb_t[(row+i)*2048 + col], aX[i]+aH[i]);
          } else {
            #pragma unroll
            for (int i=0;i<4;i++){
              cstf(&gb_t[(row+i)*2048 + col], aX[i]);
              cstf(&gb_t[(row+i)*2048 + col + 512], aH[i]);
            }
          }
        } else {
          const float* gxer = p.gxe + (size_t)((t*2 + (b>>4))*16 + (b&15))*1536;
          for (int i = tid - 384; i < 1536; i += 128) gxe_s[i] = gxer[i];
        }
      }
      gridbar32(p.arr, ++idx);

      // ---------------- ATTN phase (single block per batch) ----------------
      float* hf_w = p.hf + (size_t)(t+1)*16384;
      unsigned short* hpk_w = p.hpk + (size_t)(t+1)*16384;
      float* cf_w = p.cf + (size_t)(t+1)*16384;
      unsigned short* cpk_w = p.cpk + (size_t)(t+1)*16384;

      // phase 0: GRU combine -> h(t)
      {
        int jj = tid;
        const float* gbr = gb_t + b*2048;
        float s0 = gbr[jj], s1 = gbr[512+jj], x2 = gbr[1024+jj], y2 = gbr[1536+jj];
        float e0 = gxe_s[jj], e1 = gxe_s[512+jj], e2 = gxe_s[1024+jj];
        float r = sigm_(e0 + s0);
        float z = sigm_(e1 + s1);
        float n = tanh_(e2 + x2 + r*(y2 + bh2r));
        float hold = h_s[jj];
        float hn = (1.f - z)*n + z*hold;
        __syncthreads();               // everyone done reading h_s(t-1)
        h_s[jj] = hn;
        cstf(&hf_w[b*512+jj], hn); csts(&hpk_w[pkidx(b,jj)], f2bf(hn));
      }
      __syncthreads();

      // phase 1: hq = h @ Wq (weights in registers; h_s broadcast reads)
      {
        int k = tid & 63, pr = tid >> 6;
        float a = 0.f;
        #pragma unroll
        for (int c=0;c<8;c++){
          #pragma unroll
          for (int j=0;j<8;j++) a += h_s[pr*64 + c*8 + j]*bf2f((unsigned short)wqreg[c][j]);
        }
        hq_part[pr][k] = a;
      }
      __syncthreads();
      if (tid < 64){
        float a = 0.f;
        #pragma unroll
        for (int pr=0;pr<8;pr++) a += hq_part[pr][tid];
        hq_s[tid] = a;
      }
      __syncthreads();

      // phase 2: scores + exp (cov in register; pre row = one 128B line)
      float c_old = c_reg, p_val = 0.f;
      if (tid < 400){
        const unsigned short* prow = p.pre + ((size_t)b*400 + tid)*64;
        float a = 0.f;
        #pragma unroll
        for (int kk=0; kk<8; kk++){
          bf16x8 v = *(const bf16x8*)(prow + kk*8);
          #pragma unroll
          for (int j=0;j<8;j++){
            int k = kk*8 + j;
            float e = bf2f((unsigned short)v[j]) + hq_s[k] + c_old*wv_s[k];
            a += tanh_(e)*wv_s[64+k];
          }
        }
        p_val = padv ? 0.f : __expf(a);
        p_s[tid] = p_val;
      }
      float total = blockReduceSum((tid < 400) ? p_val : 0.f, redw, tid);
      float inv_total = 1.f/total;

      // phase 3: attn, cov (register) update, cov_loss
      float cl = 0.f;
      float inv_t = 1.f/(float)(t < 1 ? 1 : t);
      if (tid < 400){
        float attnv = p_val*inv_total;
        p.out_copypred[((size_t)b*64 + t)*400 + tid] = attnv;
        if (t == 63) p.out_attnlast[b*400+tid] = attnv;
        cl = fminf(attnv, c_old*inv_t);
        c_reg = c_old + attnv;
      }
      float cls = blockReduceSum(cl, redw, tid);
      if (tid == 0) p.out_covloss[b*64 + t] = cls;

      // phase 4: ctx = attn @ enc ; wave w owns s in [w*50, w*50+50),
      // lane owns 8 dims (bf16x8 coalesced); LDS reduce over 8 waves.
      {
        int wib = tid >> 6, lane = tid & 63;
        float acc[8] = {0.f,0.f,0.f,0.f,0.f,0.f,0.f,0.f};
        const unsigned short* ebase = p.enc + (size_t)(b*400)*512 + lane*8;
        #pragma unroll 2
        for (int ss = wib*50; ss < wib*50 + 50; ++ss){
          bf16x8 v = *(const bf16x8*)(ebase + (size_t)ss*512);
          float pw = p_s[ss];
          #pragma unroll
          for (int j=0;j<8;j++) acc[j] += pw*bf2f((unsigned short)v[j]);
        }
        #pragma unroll
        for (int j=0;j<8;j++) cred[wib][lane*8+j] = acc[j];
      }
      __syncthreads();
      {
        float cx = 0.f;
        #pragma unroll
        for (int w2=0;w2<8;w2++) cx += cred[w2][tid];
        cx *= inv_total;
        cstf(&cf_w[b*512+tid], cx);
        csts(&cpk_w[pkidx(b,tid)], f2bf(cx));
        if (t == 63) p.out_ctxf[b*512+tid] = cx;
      }
      gridbar32(p.arr, ++idx);
    }
  }

  // -------- tail on all 256 blocks: readout GEMM (+fused maxout) & copy_gate
  {
    int wslot = blockIdx.x*8 + (tid>>6);   // 0..2047
    int lane = tid & 63;

    // readout: 4096 jobs = 128 mtg x 32 nt ; K = 1536 (emb|h|ctx)
    for (int job = wslot; job < 4096; job += 2048){
      int nt = job & 31, mtg = job >> 5;
      int t = mtg >> 1, half = mtg & 1;
      f32x4 acc = {0.f,0.f,0.f,0.f};
      const bf16x8* wp = (const bf16x8*)p.wr + (size_t)(nt*48)*64 + lane;
      const bf16x8* ae = (const bf16x8*)p.emb + (size_t)(mtg*16)*64 + lane;
      const bf16x8* ah = (const bf16x8*)(p.hpk + (size_t)(t+1)*16384) + (size_t)(half*16)*64 + lane;
      const bf16x8* ac = (const bf16x8*)(p.cpk + (size_t)(t+1)*16384) + (size_t)(half*16)*64 + lane;
      #pragma unroll
      for (int kt=0; kt<16; kt++)
        acc = __builtin_amdgcn_mfma_f32_16x16x32_bf16(ae[kt*64], wp[kt*64], acc, 0,0,0);
      #pragma unroll
      for (int kt=0; kt<16; kt++)
        acc = __builtin_amdgcn_mfma_f32_16x16x32_bf16(ah[kt*64], wp[(16+kt)*64], acc, 0,0,0);
      #pragma unroll
      for (int kt=0; kt<16; kt++)
        acc = __builtin_amdgcn_mfma_f32_16x16x32_bf16(ac[kt*64], wp[(32+kt)*64], acc, 0,0,0);
      int colL = nt*16 + (lane&15);
      int b0 = half*16 + (lane>>4)*4;
      #pragma unroll
      for (int i=0;i<4;i++){
        float v = acc[i] + p.bread[colL];
        float o = __shfl_xor(v, 1, 64);
        if (!(lane & 1)){
          p.out_pred[((size_t)(b0+i)*64 + t)*256 + nt*8 + ((lane&15)>>1)] = fmaxf(v, o);
        }
      }
    }

    // copy_gate: 2048 jobs = 32 b x 64 t
    {
      int b2 = wslot >> 6, t = wslot & 63;
      const float* hfr = p.hf + (size_t)(t+1)*16384 + b2*512;
      const float* cfr = p.cf + (size_t)(t+1)*16384 + b2*512;
      float acc = 0.f;
      #pragma unroll
      for (int i=0;i<16;i++){
        int j = i*64 + lane;
        float x = (j < 512) ? hfr[j] : cfr[j-512];
        acc += x * p.Wcopy[j];
      }
      #pragma unroll
      for (int off=32; off>0; off>>=1) acc += __shfl_down(acc, off, 64);
      if (lane == 0) p.out_gate[b2*64 + t] = sigm_(acc + p.bcopy[0]);
    }
  }
}

// ---------------- host ----------------
extern "C" void kernel_launch(void* const* d_in, const int* in_sizes, int n_in,
                              void* d_out, int out_size, void* d_ws, size_t ws_size,
                              hipStream_t stream) {
  const int*   tgt     = (const int*)  d_in[0];
  const int*   src     = (const int*)  d_in[1];
  const float* enc     = (const float*)d_in[2];
  const float* hidden  = (const float*)d_in[3];
  const float* wemb    = (const float*)d_in[4];
  const float* W_init  = (const float*)d_in[5];
  const float* b_init  = (const float*)d_in[6];
  const float* Wx      = (const float*)d_in[7];
  const float* Wh      = (const float*)d_in[8];
  const float* bx      = (const float*)d_in[9];
  const float* bh      = (const float*)d_in[10];
  const float* Wc      = (const float*)d_in[11];
  const float* Wq      = (const float*)d_in[12];
  const float* w_cov   = (const float*)d_in[13];
  const float* v_att   = (const float*)d_in[14];
  const float* W_copy  = (const float*)d_in[15];
  const float* b_copy  = (const float*)d_in[16];
  const float* W_read  = (const float*)d_in[17];
  const float* b_read  = (const float*)d_in[18];

  float* out0 = (float*)d_out;            // pred [32,64,256]
  float* out1 = out0 + 524288;            // attn_last [32,400]
  float* out2 = out0 + 537088;            // ctx_f [32,512]
  float* out3 = out0 + 553472;            // copy_pred [32,64,400]
  float* out4 = out0 + 1372672;           // copy_gate [32,64,1]
  float* out5 = out0 + 1374720;           // coverage_pred [32,64]

  uint8_t* w = (uint8_t*)d_ws;
  unsigned short* emb_pk = (unsigned short*)(w);              // 2,097,152 B
  unsigned short* enc_bf = (unsigned short*)(w + 2097152);    // 13,107,200
  unsigned short* pre_t  = (unsigned short*)(w + 15204352);   // 1,638,400 ([b][s][64])
  unsigned short* wxe_pk = (unsigned short*)(w + 16842752);   // 1,572,864 (Wx rows 0:512)
  unsigned short* wxc_pk = (unsigned short*)(w + 18415616);   // 1,572,864 (Wx rows 512:1024)
  unsigned short* wh_pk  = (unsigned short*)(w + 19988480);   // 1,572,864
  unsigned short* wr_pk  = (unsigned short*)(w + 21561344);   // 1,572,864
  unsigned short* wq_t   = (unsigned short*)(w + 23134208);   // 65,536 ([k][d])
  float* gxe    = (float*)(w + 23199744);                     // 12,582,912 ([2048][1536])
  float* gb_sl  = (float*)(w + 35782656);                     // 64 x 262,144 = 16,777,216
  unsigned short* hpk_sl = (unsigned short*)(w + 52559872);   // 65 x 32,768 = 2,129,920
  unsigned short* cpk_sl = (unsigned short*)(w + 54689792);   // 2,129,920
  float* hf_sl  = (float*)(w + 56819712);                     // 65 x 65,536 = 4,259,840
  float* cf_sl  = (float*)(w + 61079552);                     // 4,259,840
  int*   arr    = (int*)  (w + 65339392);                     // barrier lines

  // init
  k_pack<<<384, 256, 0, stream>>>(Wx, wxe_pk, 1536, 512);
  k_pack<<<384, 256, 0, stream>>>(Wx + (size_t)512*1536, wxc_pk, 1536, 512);
  k_pack<<<384, 256, 0, stream>>>(Wh, wh_pk, 1536, 512);
  k_pack<<<384, 256, 0, stream>>>(W_read, wr_pk, 512, 1536);
  k_misc<<<145, 256, 0, stream>>>(Wq, wq_t, arr);
  k_emb<<<2048, 256, 0, stream>>>(tgt, wemb, emb_pk);
  k_pre<<<12800, 256, 0, stream>>>(enc, Wc, pre_t, enc_bf);
  k_h0<<<32, 512, 0, stream>>>(hidden, W_init, b_init, hf_sl, hpk_sl, cf_sl, cpk_sl);
  k_gxe<<<3072, 256, 0, stream>>>(emb_pk, wxe_pk, bx, bh, gxe);

  PP p;
  p.emb = emb_pk; p.wxc = wxc_pk; p.wh = wh_pk; p.wr = wr_pk; p.wq = wq_t;
  p.pre = pre_t; p.enc = enc_bf; p.gxe = gxe;
  p.hpk = hpk_sl; p.cpk = cpk_sl;
  p.gb = gb_sl;
  p.hf = hf_sl; p.cf = cf_sl;
  p.Wcopy = W_copy; p.bcopy = b_copy; p.bh = bh; p.bread = b_read;
  p.wcov = w_cov; p.vatt = v_att; p.src = src;
  p.out_pred = out0; p.out_attnlast = out1; p.out_ctxf = out2;
  p.out_copypred = out3; p.out_gate = out4; p.out_covloss = out5;
  p.arr = arr;

  void* kargs[] = { (void*)&p };
  hipLaunchCooperativeKernel((const void*)k_steps, dim3(256), dim3(512), kargs, 0, stream);
}